// Round 3
// baseline (153.387 us; speedup 1.0000x reference)
//
#include <hip/hip_runtime.h>
#include <hip/hip_bf16.h>

#define TT 4
#define DD 384
#define HH0 160
#define HH1 128
#define HH2 96
#define NB 2048
#define NA 64
#define NN (NB*NA)

using bhalf8 = __attribute__((ext_vector_type(8))) __bf16;
using f32x4  = __attribute__((ext_vector_type(4))) float;

__device__ __forceinline__ unsigned short f2b(float f) {
  __hip_bfloat16 h = __float2bfloat16(f);
  union { __hip_bfloat16 h; unsigned short u; } c; c.h = h; return c.u;
}
__device__ __forceinline__ float b2f(unsigned short u) {
  union { unsigned int i; float f; } c; c.i = ((unsigned int)u) << 16; return c.f;
}
// fast CELU: alpha=0.1; exp-1 instead of expm1 (bf16 output swamps the error)
__device__ __forceinline__ float celu_f(float v) {
  return v > 0.f ? v : 0.1f * (__expf(v * 10.f) - 1.f);
}

// ---------------- small prep kernels ----------------

__global__ void k_count(const int* __restrict__ species, int* __restrict__ counts,
                        float* __restrict__ out_sp) {
  __shared__ int lcnt[4];
  int tid = threadIdx.x;
  if (tid < 4) lcnt[tid] = 0;
  __syncthreads();
  int i = blockIdx.x * 256 + tid;
  int s = species[i];
  out_sp[i] = (float)s;
  atomicAdd(&lcnt[s], 1);
  __syncthreads();
  if (tid < 4) atomicAdd(&counts[tid], lcnt[tid]);
}

__global__ void k_scatter(const int* __restrict__ species, const int* __restrict__ counts,
                          int* __restrict__ cursors, int* __restrict__ sorted) {
  __shared__ int lcnt[4];
  __shared__ int lbase[4];
  int tid = threadIdx.x;
  if (tid < 4) lcnt[tid] = 0;
  __syncthreads();
  int i = blockIdx.x * 256 + tid;
  int s = species[i];
  int lpos = atomicAdd(&lcnt[s], 1);
  __syncthreads();
  if (tid < 4) {
    int offs = 0;
    #pragma unroll
    for (int t = 0; t < 4; ++t) if (t < tid) offs += counts[t];
    lbase[tid] = offs + atomicAdd(&cursors[tid], lcnt[tid]);
  }
  __syncthreads();
  sorted[lbase[s] + lpos] = i;
}

// convert weights fp32 -> bf16, transposed to [type][neuron][k]
__global__ void k_wcvt(const float* __restrict__ W0, const float* __restrict__ W1,
                       const float* __restrict__ W2, const float* __restrict__ W3,
                       unsigned short* __restrict__ W0T, unsigned short* __restrict__ W1T,
                       unsigned short* __restrict__ W2T, unsigned short* __restrict__ W3B) {
  int id = blockIdx.x * 256 + threadIdx.x;
  if (id < 4*160*384) {
    int t = id / (160*384); int r = id % (160*384); int n = r / 384; int k = r % 384;
    W0T[id] = f2b(W0[t*384*160 + k*160 + n]);
  } else if ((id -= 4*160*384) < 4*128*160) {
    int t = id / (128*160); int r = id % (128*160); int n = r / 160; int k = r % 160;
    W1T[id] = f2b(W1[t*160*128 + k*128 + n]);
  } else if ((id -= 4*128*160) < 4*96*128) {
    int t = id / (96*128); int r = id % (96*128); int n = r / 128; int k = r % 128;
    W2T[id] = f2b(W2[t*128*96 + k*96 + n]);
  } else if ((id -= 4*96*128) < 4*96) {
    int t = id / 96; int k = id % 96;
    W3B[id] = f2b(W3[t*96 + k]);
  }
}

// ---------------- fused MFMA MLP ----------------
// LDS carve (bytes), total 50176:
//   sX  ushort[64][392]  at 0        (row stride 784B = 196 dw; 196%32==4 -> conflict-free b128)
//   sH0 ushort[64][168]  at 0        (overlays sX after L0 done)
//   sH1 ushort[64][136]  at 21504
//   sH2 ushort[64][104]  at 0        (overlays sH0 after L1 MFMA done)
// Weights load global->VGPR (L2-resident, 753 KB).
// Staging: each thread issues all 24 float4 loads up front (98 KB/block in
// flight) -> one barrier -> L0 runs with zero internal barriers.

__global__ __launch_bounds__(256, 2) void k_mlp(
    const float* __restrict__ aev, const int* __restrict__ sorted,
    const int* __restrict__ counts,
    const unsigned short* __restrict__ W0T, const unsigned short* __restrict__ W1T,
    const unsigned short* __restrict__ W2T, const unsigned short* __restrict__ W3B,
    const float* __restrict__ b0, const float* __restrict__ b1,
    const float* __restrict__ b2, const float* __restrict__ b3,
    float* __restrict__ atom_out)
{
  int type = blockIdx.x;
  int tile = blockIdx.y;
  int c0 = counts[0], c1 = counts[1], c2 = counts[2], c3 = counts[3];
  int cnt = (type == 0) ? c0 : (type == 1) ? c1 : (type == 2) ? c2 : c3;
  if (tile * 64 >= cnt) return;
  int off = 0;
  if (type > 0) off += c0;
  if (type > 1) off += c1;
  if (type > 2) off += c2;

  __shared__ uint4 smem4[50176 / 16];
  __shared__ int aidx[64];
  unsigned char* smem = (unsigned char*)smem4;
  unsigned short* sX  = (unsigned short*)(smem + 0);       // [64][392]
  unsigned short* sH0 = (unsigned short*)(smem + 0);       // [64][168]
  unsigned short* sH2 = (unsigned short*)(smem + 0);       // [64][104]
  unsigned short* sH1 = (unsigned short*)(smem + 21504);   // [64][136]

  int tid = threadIdx.x;
  int base = off + tile * 64;
  int nvalid = min(64, cnt - tile * 64);
  if (tid < 64) aidx[tid] = sorted[base + min(tid, nvalid - 1)];
  __syncthreads();                                          // barrier 1

  int lane = tid & 63;
  int w = tid >> 6;
  int wm = w & 1, wn = w >> 1;
  int l15 = lane & 15, lk = lane >> 4;

  // ---------- stage full X tile: 64 atoms x 384 k, one burst ----------
  {
    int a = tid >> 2, q = tid & 3;
    const float* src = aev + (size_t)aidx[a] * DD + q * 96;
    float4 f[24];
    #pragma unroll
    for (int i = 0; i < 24; ++i) f[i] = ((const float4*)src)[i];
    #pragma unroll
    for (int j = 0; j < 12; ++j) {
      union { unsigned short us[8]; uint4 v; } t;
      #pragma unroll
      for (int h = 0; h < 2; ++h) {
        float4 ff = f[j * 2 + h];
        t.us[h*4+0] = f2b(ff.x); t.us[h*4+1] = f2b(ff.y);
        t.us[h*4+2] = f2b(ff.z); t.us[h*4+3] = f2b(ff.w);
      }
      *(uint4*)&sX[a * 392 + q * 96 + j * 8] = t.v;
    }
  }
  __syncthreads();                                          // barrier 2

  const unsigned short* w0b = W0T + type * (160 * 384);
  const unsigned short* w1b = W1T + type * (128 * 160);
  const unsigned short* w2b = W2T + type * (96 * 128);
  const unsigned short* b0p = w0b + (size_t)(wn * 80 + l15) * 384 + lk * 8;
  const unsigned short* b1p = w1b + (size_t)(wn * 64 + l15) * 160 + lk * 8;
  const unsigned short* b2p = w2b + (size_t)(wn * 48 + l15) * 128 + lk * 8;

  // ---------- Layer 0: [64 x 384] @ [384 x 160], no internal barriers ----------
  f32x4 acc0[2][5];
  #pragma unroll
  for (int mt = 0; mt < 2; ++mt)
    #pragma unroll
    for (int nt = 0; nt < 5; ++nt) acc0[mt][nt] = f32x4{0.f, 0.f, 0.f, 0.f};

  #pragma unroll
  for (int kc = 0; kc < 6; ++kc) {
    #pragma unroll
    for (int ks = 0; ks < 2; ++ks) {
      int k0 = kc * 64 + ks * 32 + lk * 8;
      bhalf8 af[2], bfv[5];
      #pragma unroll
      for (int mt = 0; mt < 2; ++mt)
        af[mt] = *(const bhalf8*)&sX[(wm*32 + mt*16 + l15) * 392 + k0];
      #pragma unroll
      for (int nt = 0; nt < 5; ++nt)
        bfv[nt] = *(const bhalf8*)&b0p[nt * 16 * 384 + kc * 64 + ks * 32];
      #pragma unroll
      for (int mt = 0; mt < 2; ++mt)
        #pragma unroll
        for (int nt = 0; nt < 5; ++nt)
          acc0[mt][nt] = __builtin_amdgcn_mfma_f32_16x16x32_bf16(af[mt], bfv[nt], acc0[mt][nt], 0, 0, 0);
    }
  }
  __syncthreads();                                          // barrier 3 (sX dead)

  // epilogue L0 -> sH0 (overlays sX)
  #pragma unroll
  for (int mt = 0; mt < 2; ++mt)
    #pragma unroll
    for (int nt = 0; nt < 5; ++nt) {
      int col = wn*80 + nt*16 + l15;
      float bias = b0[type * HH0 + col];
      #pragma unroll
      for (int i = 0; i < 4; ++i) {
        int row = wm*32 + mt*16 + lk*4 + i;
        sH0[row * 168 + col] = f2b(celu_f(acc0[mt][nt][i] + bias));
      }
    }
  __syncthreads();                                          // barrier 4

  // ---------- Layer 1: [64 x 160] @ [160 x 128] ----------
  f32x4 acc1[2][4];
  #pragma unroll
  for (int mt = 0; mt < 2; ++mt)
    #pragma unroll
    for (int nt = 0; nt < 4; ++nt) acc1[mt][nt] = f32x4{0.f, 0.f, 0.f, 0.f};

  #pragma unroll
  for (int kc = 0; kc < 5; ++kc) {
    bhalf8 af[2], bfv[4];
    #pragma unroll
    for (int mt = 0; mt < 2; ++mt)
      af[mt] = *(const bhalf8*)&sH0[(wm*32 + mt*16 + l15) * 168 + kc * 32 + lk * 8];
    #pragma unroll
    for (int nt = 0; nt < 4; ++nt)
      bfv[nt] = *(const bhalf8*)&b1p[nt * 16 * 160 + kc * 32];
    #pragma unroll
    for (int mt = 0; mt < 2; ++mt)
      #pragma unroll
      for (int nt = 0; nt < 4; ++nt)
        acc1[mt][nt] = __builtin_amdgcn_mfma_f32_16x16x32_bf16(af[mt], bfv[nt], acc1[mt][nt], 0, 0, 0);
  }
  // epilogue L1 -> sH1 (no alias with sH0; no barrier needed before writes)
  #pragma unroll
  for (int mt = 0; mt < 2; ++mt)
    #pragma unroll
    for (int nt = 0; nt < 4; ++nt) {
      int col = wn*64 + nt*16 + l15;
      float bias = b1[type * HH1 + col];
      #pragma unroll
      for (int i = 0; i < 4; ++i) {
        int row = wm*32 + mt*16 + lk*4 + i;
        sH1[row * 136 + col] = f2b(celu_f(acc1[mt][nt][i] + bias));
      }
    }
  __syncthreads();                                          // barrier 5

  // ---------- Layer 2: [64 x 128] @ [128 x 96] ----------
  f32x4 acc2[2][3];
  #pragma unroll
  for (int mt = 0; mt < 2; ++mt)
    #pragma unroll
    for (int nt = 0; nt < 3; ++nt) acc2[mt][nt] = f32x4{0.f, 0.f, 0.f, 0.f};

  #pragma unroll
  for (int kc = 0; kc < 4; ++kc) {
    bhalf8 af[2], bfv[3];
    #pragma unroll
    for (int mt = 0; mt < 2; ++mt)
      af[mt] = *(const bhalf8*)&sH1[(wm*32 + mt*16 + l15) * 136 + kc * 32 + lk * 8];
    #pragma unroll
    for (int nt = 0; nt < 3; ++nt)
      bfv[nt] = *(const bhalf8*)&b2p[nt * 16 * 128 + kc * 32];
    #pragma unroll
    for (int mt = 0; mt < 2; ++mt)
      #pragma unroll
      for (int nt = 0; nt < 3; ++nt)
        acc2[mt][nt] = __builtin_amdgcn_mfma_f32_16x16x32_bf16(af[mt], bfv[nt], acc2[mt][nt], 0, 0, 0);
  }
  // epilogue L2 -> sH2 (overlays sH0; sH0's last readers finished before barrier 5)
  #pragma unroll
  for (int mt = 0; mt < 2; ++mt)
    #pragma unroll
    for (int nt = 0; nt < 3; ++nt) {
      int col = wn*48 + nt*16 + l15;
      float bias = b2[type * HH2 + col];
      #pragma unroll
      for (int i = 0; i < 4; ++i) {
        int row = wm*32 + mt*16 + lk*4 + i;
        sH2[row * 104 + col] = f2b(celu_f(acc2[mt][nt][i] + bias));
      }
    }
  __syncthreads();                                          // barrier 6

  // ---------- Layer 3: [64 x 96] @ [96 x 1], b128 reads ----------
  {
    int atom = tid >> 2;
    int q = tid & 3;
    const unsigned short* w3 = W3B + type * 96 + q * 24;
    const unsigned short* hrow = sH2 + atom * 104 + q * 24;
    float s = 0.f;
    #pragma unroll
    for (int i = 0; i < 3; ++i) {
      union { bhalf8 v; unsigned short u[8]; } hu, wu;
      hu.v = *(const bhalf8*)&hrow[i * 8];
      wu.v = *(const bhalf8*)&w3[i * 8];
      #pragma unroll
      for (int j = 0; j < 8; ++j)
        s += b2f(hu.u[j]) * b2f(wu.u[j]);
    }
    s += __shfl_xor(s, 1);
    s += __shfl_xor(s, 2);
    if (q == 0 && atom < nvalid)
      atom_out[aidx[atom]] = s + b3[type];
  }
}

__global__ void k_reduce(const float* __restrict__ atom_out, float* __restrict__ out_e) {
  int mol = blockIdx.x;
  int lane = threadIdx.x;
  float v = atom_out[mol * 64 + lane];
  #pragma unroll
  for (int m = 32; m >= 1; m >>= 1) v += __shfl_xor(v, m);
  if (lane == 0) out_e[mol] = v;
}

// ---------------- launch ----------------

extern "C" void kernel_launch(void* const* d_in, const int* in_sizes, int n_in,
                              void* d_out, int out_size, void* d_ws, size_t ws_size,
                              hipStream_t stream) {
  const int*   species = (const int*)d_in[0];
  const float* aev = (const float*)d_in[1];
  const float* W0 = (const float*)d_in[2];
  const float* b0 = (const float*)d_in[3];
  const float* W1 = (const float*)d_in[4];
  const float* b1 = (const float*)d_in[5];
  const float* W2 = (const float*)d_in[6];
  const float* b2 = (const float*)d_in[7];
  const float* W3 = (const float*)d_in[8];
  const float* b3 = (const float*)d_in[9];
  float* out = (float*)d_out;

  unsigned char* ws = (unsigned char*)d_ws;
  int* counts = (int*)(ws + 0);                         // [4] counts + pad + [4] cursors
  int* sorted = (int*)(ws + 64);                        // int[NN]
  float* atom_out = (float*)(ws + 524352);              // float[NN]
  unsigned short* W0T = (unsigned short*)(ws + 1048640);
  unsigned short* W1T = (unsigned short*)(ws + 1540160);
  unsigned short* W2T = (unsigned short*)(ws + 1704000);
  unsigned short* W3B = (unsigned short*)(ws + 1802304);

  hipMemsetAsync(counts, 0, 48, stream);
  k_count<<<NN / 256, 256, 0, stream>>>(species, counts, out);
  k_scatter<<<NN / 256, 256, 0, stream>>>(species, counts, counts + 8, sorted);
  k_wcvt<<<1474, 256, 0, stream>>>(W0, W1, W2, W3, W0T, W1T, W2T, W3B);
  k_mlp<<<dim3(4, 2048), 256, 0, stream>>>(aev, sorted, counts,
        W0T, W1T, W2T, W3B, b0, b1, b2, b3, atom_out);
  k_reduce<<<NB, 64, 0, stream>>>(atom_out, out + NN);
}

// Round 4
// 130.016 us; speedup vs baseline: 1.1798x; 1.1798x over previous
//
#include <hip/hip_runtime.h>
#include <hip/hip_bf16.h>

#define TT 4
#define DD 384
#define HH0 160
#define HH1 128
#define HH2 96
#define NB 2048
#define NA 64
#define NN (NB*NA)

using bhalf8 = __attribute__((ext_vector_type(8))) __bf16;
using f32x4  = __attribute__((ext_vector_type(4))) float;

#define AS1 __attribute__((address_space(1)))
#define AS3 __attribute__((address_space(3)))

__device__ __forceinline__ void gl_lds16(const float* g, unsigned char* l) {
  __builtin_amdgcn_global_load_lds((const AS1 void*)g, (AS3 void*)l, 16, 0, 0);
}

__device__ __forceinline__ unsigned short f2b(float f) {
  __hip_bfloat16 h = __float2bfloat16(f);
  union { __hip_bfloat16 h; unsigned short u; } c; c.h = h; return c.u;
}
__device__ __forceinline__ float b2f(unsigned short u) {
  union { unsigned int i; float f; } c; c.i = ((unsigned int)u) << 16; return c.f;
}
__device__ __forceinline__ float celu_f(float v) {
  return v > 0.f ? v : 0.1f * (__expf(v * 10.f) - 1.f);
}

// ---------------- small prep kernels ----------------

__global__ void k_count(const int* __restrict__ species, int* __restrict__ counts,
                        float* __restrict__ out_sp) {
  __shared__ int lcnt[4];
  int tid = threadIdx.x;
  if (tid < 4) lcnt[tid] = 0;
  __syncthreads();
  int i = blockIdx.x * 256 + tid;
  int s = species[i];
  out_sp[i] = (float)s;
  atomicAdd(&lcnt[s], 1);
  __syncthreads();
  if (tid < 4) atomicAdd(&counts[tid], lcnt[tid]);
}

__global__ void k_scatter(const int* __restrict__ species, const int* __restrict__ counts,
                          int* __restrict__ cursors, int* __restrict__ sorted) {
  __shared__ int lcnt[4];
  __shared__ int lbase[4];
  int tid = threadIdx.x;
  if (tid < 4) lcnt[tid] = 0;
  __syncthreads();
  int i = blockIdx.x * 256 + tid;
  int s = species[i];
  int lpos = atomicAdd(&lcnt[s], 1);
  __syncthreads();
  if (tid < 4) {
    int offs = 0;
    #pragma unroll
    for (int t = 0; t < 4; ++t) if (t < tid) offs += counts[t];
    lbase[tid] = offs + atomicAdd(&cursors[tid], lcnt[tid]);
  }
  __syncthreads();
  sorted[lbase[s] + lpos] = i;
}

// convert weights fp32 -> bf16, transposed to [type][neuron][k]
__global__ void k_wcvt(const float* __restrict__ W0, const float* __restrict__ W1,
                       const float* __restrict__ W2, const float* __restrict__ W3,
                       unsigned short* __restrict__ W0T, unsigned short* __restrict__ W1T,
                       unsigned short* __restrict__ W2T, unsigned short* __restrict__ W3B) {
  int id = blockIdx.x * 256 + threadIdx.x;
  if (id < 4*160*384) {
    int t = id / (160*384); int r = id % (160*384); int n = r / 384; int k = r % 384;
    W0T[id] = f2b(W0[t*384*160 + k*160 + n]);
  } else if ((id -= 4*160*384) < 4*128*160) {
    int t = id / (128*160); int r = id % (128*160); int n = r / 160; int k = r % 160;
    W1T[id] = f2b(W1[t*160*128 + k*128 + n]);
  } else if ((id -= 4*128*160) < 4*96*128) {
    int t = id / (96*128); int r = id % (96*128); int n = r / 128; int k = r % 128;
    W2T[id] = f2b(W2[t*128*96 + k*96 + n]);
  } else if ((id -= 4*96*128) < 4*96) {
    int t = id / 96; int k = id % 96;
    W3B[id] = f2b(W3[t*96 + k]);
  }
}

// ---------------- fused MFMA MLP ----------------
// LDS carve (bytes), total 38912 (+256 aidx):  -> 4 blocks/CU
//   stg: [0, 32768)  2 x fp32 chunk buffers [64 atoms][256 B], LINEAR for
//        global_load_lds; XOR-swizzle (col ^ ((row&7)<<4)) applied on the
//        GLOBAL source and on the LDS reads (rule #21 both-sides).
//   sH0 ushort[64][168] at 0      (overlays stg after L0 done)
//   sH1 ushort[64][136] at 21504
//   sH2 ushort[64][104] at 0      (overlays sH0 after L1 MFMAs done)
// Weights: global->VGPR (L2-resident).
// L0 pipeline: chunks staged 2-ahead via global_load_lds; counted
// s_waitcnt vmcnt(4) + raw s_barrier per phase (T3/T4).

__global__ __launch_bounds__(256, 4) void k_mlp(
    const float* __restrict__ aev, const int* __restrict__ sorted,
    const int* __restrict__ counts,
    const unsigned short* __restrict__ W0T, const unsigned short* __restrict__ W1T,
    const unsigned short* __restrict__ W2T, const unsigned short* __restrict__ W3B,
    const float* __restrict__ b0, const float* __restrict__ b1,
    const float* __restrict__ b2, const float* __restrict__ b3,
    float* __restrict__ atom_out)
{
  int type = blockIdx.x;
  int tile = blockIdx.y;
  int c0 = counts[0], c1 = counts[1], c2 = counts[2], c3 = counts[3];
  int cnt = (type == 0) ? c0 : (type == 1) ? c1 : (type == 2) ? c2 : c3;
  if (tile * 64 >= cnt) return;
  int off = 0;
  if (type > 0) off += c0;
  if (type > 1) off += c1;
  if (type > 2) off += c2;

  __shared__ uint4 smem4[38912 / 16];
  __shared__ int aidx[64];
  unsigned char* smem = (unsigned char*)smem4;
  unsigned char* stg = smem;                               // [2][64][256B] fp32
  unsigned short* sH0 = (unsigned short*)(smem + 0);       // [64][168]
  unsigned short* sH2 = (unsigned short*)(smem + 0);       // [64][104]
  unsigned short* sH1 = (unsigned short*)(smem + 21504);   // [64][136]

  int tid = threadIdx.x;
  int base = off + tile * 64;
  int nvalid = min(64, cnt - tile * 64);
  if (tid < 64) aidx[tid] = sorted[base + min(tid, nvalid - 1)];
  __syncthreads();

  int lane = tid & 63;
  int w = tid >> 6;
  int wm = w & 1, wn = w >> 1;
  int l15 = lane & 15, lk = lane >> 4;

  // ----- staging address setup (per lane) -----
  // chunk layout: row r (atom) x 256 B (64 fp32). Wave w stages atoms
  // [w*16, w*16+16): instr i covers atoms w*16+i*4 .. +4, lane l -> row
  // w*16+i*4+(l>>4), linear LDS col (l&15)*16. Lane fetches the global
  // 16 B that belongs at its linear slot: col ^ ((row&7)<<4).
  const float* gsrc0; const float* gsrc1; const float* gsrc2; const float* gsrc3;
  {
    int r4 = lane >> 4, c16 = (lane & 15) << 4;
    int r0 = w * 16 + 0 + r4, r1 = w * 16 + 4 + r4;
    int r2 = w * 16 + 8 + r4, r3 = w * 16 + 12 + r4;
    gsrc0 = aev + (size_t)aidx[r0] * DD + ((c16 ^ ((r0 & 7) << 4)) >> 2);
    gsrc1 = aev + (size_t)aidx[r1] * DD + ((c16 ^ ((r1 & 7) << 4)) >> 2);
    gsrc2 = aev + (size_t)aidx[r2] * DD + ((c16 ^ ((r2 & 7) << 4)) >> 2);
    gsrc3 = aev + (size_t)aidx[r3] * DD + ((c16 ^ ((r3 & 7) << 4)) >> 2);
  }
  unsigned char* ldsw = stg + (w * 16) * 256;   // wave-uniform

#define STAGE(kc, b) do { \
    gl_lds16(gsrc0 + (kc) * 64, ldsw + (b) * 16384 + 0 * 1024); \
    gl_lds16(gsrc1 + (kc) * 64, ldsw + (b) * 16384 + 1 * 1024); \
    gl_lds16(gsrc2 + (kc) * 64, ldsw + (b) * 16384 + 2 * 1024); \
    gl_lds16(gsrc3 + (kc) * 64, ldsw + (b) * 16384 + 3 * 1024); \
  } while (0)

  const unsigned short* w0b = W0T + type * (160 * 384);
  const unsigned short* w1b = W1T + type * (128 * 160);
  const unsigned short* w2b = W2T + type * (96 * 128);
  const unsigned short* b0p = w0b + (size_t)(wn * 80 + l15) * 384 + lk * 8;
  const unsigned short* b1p = w1b + (size_t)(wn * 64 + l15) * 160 + lk * 8;
  const unsigned short* b2p = w2b + (size_t)(wn * 48 + l15) * 128 + lk * 8;

  // A-fragment read bases (rows fixed per lane; swizzled col per k-step)
  int rowA0 = wm * 32 + 0 + l15, rowA1 = wm * 32 + 16 + l15;
  int swA0 = (rowA0 & 7) << 4,   swA1 = (rowA1 & 7) << 4;
  const unsigned char* rbA0 = stg + rowA0 * 256;
  const unsigned char* rbA1 = stg + rowA1 * 256;

  // ---------- Layer 0: [64 x 384] @ [384 x 160], async pipeline ----------
  f32x4 acc0[2][5];
  #pragma unroll
  for (int mt = 0; mt < 2; ++mt)
    #pragma unroll
    for (int nt = 0; nt < 5; ++nt) acc0[mt][nt] = f32x4{0.f, 0.f, 0.f, 0.f};

  STAGE(0, 0);
  STAGE(1, 1);

  #pragma unroll
  for (int kc = 0; kc < 6; ++kc) {
    if (kc < 5) asm volatile("s_waitcnt vmcnt(4)" ::: "memory");
    else        asm volatile("s_waitcnt vmcnt(0)" ::: "memory");
    __builtin_amdgcn_sched_barrier(0);
    __builtin_amdgcn_s_barrier();          // chunk kc visible to all waves

    int boff = (kc & 1) * 16384;
    #pragma unroll
    for (int ks = 0; ks < 2; ++ks) {
      int kb = ks * 128 + lk * 32;         // byte col of 8-fp32 window
      bhalf8 af[2], bfv[5];
      {
        float4 p0 = *(const float4*)(rbA0 + boff + (kb ^ swA0));
        float4 p1 = *(const float4*)(rbA0 + boff + ((kb + 16) ^ swA0));
        union { unsigned short us[8]; bhalf8 v; } t;
        t.us[0]=f2b(p0.x); t.us[1]=f2b(p0.y); t.us[2]=f2b(p0.z); t.us[3]=f2b(p0.w);
        t.us[4]=f2b(p1.x); t.us[5]=f2b(p1.y); t.us[6]=f2b(p1.z); t.us[7]=f2b(p1.w);
        af[0] = t.v;
      }
      {
        float4 p0 = *(const float4*)(rbA1 + boff + (kb ^ swA1));
        float4 p1 = *(const float4*)(rbA1 + boff + ((kb + 16) ^ swA1));
        union { unsigned short us[8]; bhalf8 v; } t;
        t.us[0]=f2b(p0.x); t.us[1]=f2b(p0.y); t.us[2]=f2b(p0.z); t.us[3]=f2b(p0.w);
        t.us[4]=f2b(p1.x); t.us[5]=f2b(p1.y); t.us[6]=f2b(p1.z); t.us[7]=f2b(p1.w);
        af[1] = t.v;
      }
      #pragma unroll
      for (int nt = 0; nt < 5; ++nt)
        bfv[nt] = *(const bhalf8*)&b0p[nt * 16 * 384 + kc * 64 + ks * 32];
      #pragma unroll
      for (int mt = 0; mt < 2; ++mt)
        #pragma unroll
        for (int nt = 0; nt < 5; ++nt)
          acc0[mt][nt] = __builtin_amdgcn_mfma_f32_16x16x32_bf16(af[mt], bfv[nt], acc0[mt][nt], 0, 0, 0);
    }

    asm volatile("s_waitcnt lgkmcnt(0)" ::: "memory");
    __builtin_amdgcn_s_barrier();          // all reads of this buffer done
    if (kc < 4) STAGE(kc + 2, kc & 1);     // overwrite just-freed buffer
  }
#undef STAGE

  // epilogue L0 -> sH0 (overlays stg; all stg reads done past last barrier)
  #pragma unroll
  for (int mt = 0; mt < 2; ++mt)
    #pragma unroll
    for (int nt = 0; nt < 5; ++nt) {
      int col = wn*80 + nt*16 + l15;
      float bias = b0[type * HH0 + col];
      #pragma unroll
      for (int i = 0; i < 4; ++i) {
        int row = wm*32 + mt*16 + lk*4 + i;
        sH0[row * 168 + col] = f2b(celu_f(acc0[mt][nt][i] + bias));
      }
    }
  __syncthreads();

  // ---------- Layer 1: [64 x 160] @ [160 x 128] ----------
  f32x4 acc1[2][4];
  #pragma unroll
  for (int mt = 0; mt < 2; ++mt)
    #pragma unroll
    for (int nt = 0; nt < 4; ++nt) acc1[mt][nt] = f32x4{0.f, 0.f, 0.f, 0.f};

  #pragma unroll
  for (int kc = 0; kc < 5; ++kc) {
    bhalf8 af[2], bfv[4];
    #pragma unroll
    for (int mt = 0; mt < 2; ++mt)
      af[mt] = *(const bhalf8*)&sH0[(wm*32 + mt*16 + l15) * 168 + kc * 32 + lk * 8];
    #pragma unroll
    for (int nt = 0; nt < 4; ++nt)
      bfv[nt] = *(const bhalf8*)&b1p[nt * 16 * 160 + kc * 32];
    #pragma unroll
    for (int mt = 0; mt < 2; ++mt)
      #pragma unroll
      for (int nt = 0; nt < 4; ++nt)
        acc1[mt][nt] = __builtin_amdgcn_mfma_f32_16x16x32_bf16(af[mt], bfv[nt], acc1[mt][nt], 0, 0, 0);
  }
  // epilogue L1 -> sH1 (disjoint from sH0; no pre-barrier needed)
  #pragma unroll
  for (int mt = 0; mt < 2; ++mt)
    #pragma unroll
    for (int nt = 0; nt < 4; ++nt) {
      int col = wn*64 + nt*16 + l15;
      float bias = b1[type * HH1 + col];
      #pragma unroll
      for (int i = 0; i < 4; ++i) {
        int row = wm*32 + mt*16 + lk*4 + i;
        sH1[row * 136 + col] = f2b(celu_f(acc1[mt][nt][i] + bias));
      }
    }
  __syncthreads();

  // ---------- Layer 2: [64 x 128] @ [128 x 96] ----------
  f32x4 acc2[2][3];
  #pragma unroll
  for (int mt = 0; mt < 2; ++mt)
    #pragma unroll
    for (int nt = 0; nt < 3; ++nt) acc2[mt][nt] = f32x4{0.f, 0.f, 0.f, 0.f};

  #pragma unroll
  for (int kc = 0; kc < 4; ++kc) {
    bhalf8 af[2], bfv[3];
    #pragma unroll
    for (int mt = 0; mt < 2; ++mt)
      af[mt] = *(const bhalf8*)&sH1[(wm*32 + mt*16 + l15) * 136 + kc * 32 + lk * 8];
    #pragma unroll
    for (int nt = 0; nt < 3; ++nt)
      bfv[nt] = *(const bhalf8*)&b2p[nt * 16 * 128 + kc * 32];
    #pragma unroll
    for (int mt = 0; mt < 2; ++mt)
      #pragma unroll
      for (int nt = 0; nt < 3; ++nt)
        acc2[mt][nt] = __builtin_amdgcn_mfma_f32_16x16x32_bf16(af[mt], bfv[nt], acc2[mt][nt], 0, 0, 0);
  }
  // epilogue L2 -> sH2 (overlays sH0; its readers finished before last barrier)
  #pragma unroll
  for (int mt = 0; mt < 2; ++mt)
    #pragma unroll
    for (int nt = 0; nt < 3; ++nt) {
      int col = wn*48 + nt*16 + l15;
      float bias = b2[type * HH2 + col];
      #pragma unroll
      for (int i = 0; i < 4; ++i) {
        int row = wm*32 + mt*16 + lk*4 + i;
        sH2[row * 104 + col] = f2b(celu_f(acc2[mt][nt][i] + bias));
      }
    }
  __syncthreads();

  // ---------- Layer 3: [64 x 96] @ [96 x 1], b128 reads ----------
  {
    int atom = tid >> 2;
    int q = tid & 3;
    const unsigned short* w3 = W3B + type * 96 + q * 24;
    const unsigned short* hrow = sH2 + atom * 104 + q * 24;
    float s = 0.f;
    #pragma unroll
    for (int i = 0; i < 3; ++i) {
      union { bhalf8 v; unsigned short u[8]; } hu, wu;
      hu.v = *(const bhalf8*)&hrow[i * 8];
      wu.v = *(const bhalf8*)&w3[i * 8];
      #pragma unroll
      for (int j = 0; j < 8; ++j)
        s += b2f(hu.u[j]) * b2f(wu.u[j]);
    }
    s += __shfl_xor(s, 1);
    s += __shfl_xor(s, 2);
    if (q == 0 && atom < nvalid)
      atom_out[aidx[atom]] = s + b3[type];
  }
}

__global__ void k_reduce(const float* __restrict__ atom_out, float* __restrict__ out_e) {
  int mol = blockIdx.x;
  int lane = threadIdx.x;
  float v = atom_out[mol * 64 + lane];
  #pragma unroll
  for (int m = 32; m >= 1; m >>= 1) v += __shfl_xor(v, m);
  if (lane == 0) out_e[mol] = v;
}

// ---------------- launch ----------------

extern "C" void kernel_launch(void* const* d_in, const int* in_sizes, int n_in,
                              void* d_out, int out_size, void* d_ws, size_t ws_size,
                              hipStream_t stream) {
  const int*   species = (const int*)d_in[0];
  const float* aev = (const float*)d_in[1];
  const float* W0 = (const float*)d_in[2];
  const float* b0 = (const float*)d_in[3];
  const float* W1 = (const float*)d_in[4];
  const float* b1 = (const float*)d_in[5];
  const float* W2 = (const float*)d_in[6];
  const float* b2 = (const float*)d_in[7];
  const float* W3 = (const float*)d_in[8];
  const float* b3 = (const float*)d_in[9];
  float* out = (float*)d_out;

  unsigned char* ws = (unsigned char*)d_ws;
  int* counts = (int*)(ws + 0);                         // [4] counts + pad + [4] cursors
  int* sorted = (int*)(ws + 64);                        // int[NN]
  float* atom_out = (float*)(ws + 524352);              // float[NN]
  unsigned short* W0T = (unsigned short*)(ws + 1048640);
  unsigned short* W1T = (unsigned short*)(ws + 1540160);
  unsigned short* W2T = (unsigned short*)(ws + 1704000);
  unsigned short* W3B = (unsigned short*)(ws + 1802304);

  hipMemsetAsync(counts, 0, 48, stream);
  k_count<<<NN / 256, 256, 0, stream>>>(species, counts, out);
  k_scatter<<<NN / 256, 256, 0, stream>>>(species, counts, counts + 8, sorted);
  k_wcvt<<<1474, 256, 0, stream>>>(W0, W1, W2, W3, W0T, W1T, W2T, W3B);
  k_mlp<<<dim3(4, 2048), 256, 0, stream>>>(aev, sorted, counts,
        W0T, W1T, W2T, W3B, b0, b1, b2, b3, atom_out);
  k_reduce<<<NB, 64, 0, stream>>>(atom_out, out + NN);
}

// Round 5
// 101.629 us; speedup vs baseline: 1.5093x; 1.2793x over previous
//
#include <hip/hip_runtime.h>
#include <hip/hip_bf16.h>

#define DD 384
#define NB 2048
#define NA 64
#define NN (NB*NA)

using bhalf8 = __attribute__((ext_vector_type(8))) __bf16;
using f32x4  = __attribute__((ext_vector_type(4))) float;
typedef unsigned short u16;
typedef unsigned char u8;

#define AS1 __attribute__((address_space(1)))
#define AS3 __attribute__((address_space(3)))

__device__ __forceinline__ void gl_lds16(const void* g, void* l) {
  __builtin_amdgcn_global_load_lds((const AS1 void*)g, (AS3 void*)l, 16, 0, 0);
}

__device__ __forceinline__ u16 f2b(float f) {
  __hip_bfloat16 h = __float2bfloat16(f);
  union { __hip_bfloat16 h; u16 u; } c; c.h = h; return c.u;
}
__device__ __forceinline__ float b2f(u16 u) {
  union { unsigned int i; float f; } c; c.i = ((unsigned int)u) << 16; return c.f;
}
__device__ __forceinline__ float celu_f(float v) {
  return v > 0.f ? v : 0.1f * (__expf(v * 10.f) - 1.f);
}
__device__ __forceinline__ bhalf8 pack8(float4 a, float4 b) {
  union { u16 us[8]; bhalf8 v; } t;
  t.us[0]=f2b(a.x); t.us[1]=f2b(a.y); t.us[2]=f2b(a.z); t.us[3]=f2b(a.w);
  t.us[4]=f2b(b.x); t.us[5]=f2b(b.y); t.us[6]=f2b(b.z); t.us[7]=f2b(b.w);
  return t.v;
}

// ---------------- small prep kernels ----------------

__global__ void k_count(const int* __restrict__ species, int* __restrict__ counts,
                        float* __restrict__ out_sp) {
  __shared__ int lcnt[4];
  int tid = threadIdx.x;
  if (tid < 4) lcnt[tid] = 0;
  __syncthreads();
  int i = blockIdx.x * 256 + tid;
  int s = species[i];
  out_sp[i] = (float)s;
  atomicAdd(&lcnt[s], 1);
  __syncthreads();
  if (tid < 4) atomicAdd(&counts[tid], lcnt[tid]);
}

__global__ void k_scatter(const int* __restrict__ species, const int* __restrict__ counts,
                          int* __restrict__ cursors, int* __restrict__ sorted) {
  __shared__ int lcnt[4];
  __shared__ int lbase[4];
  int tid = threadIdx.x;
  if (tid < 4) lcnt[tid] = 0;
  __syncthreads();
  int i = blockIdx.x * 256 + tid;
  int s = species[i];
  int lpos = atomicAdd(&lcnt[s], 1);
  __syncthreads();
  if (tid < 4) {
    int offs = 0;
    #pragma unroll
    for (int t = 0; t < 4; ++t) if (t < tid) offs += counts[t];
    lbase[tid] = offs + atomicAdd(&cursors[tid], lcnt[tid]);
  }
  __syncthreads();
  sorted[lbase[s] + lpos] = i;
}

// Build LDS byte-images of the weights (bf16), swizzles baked in:
//  W0img [t][kc=6][row 160][64 slots]: slot jj holds k = kc*64 + ((2jj ^ m(r))>>1),
//        m(r) = ((r&7)<<4) ^ ((r&8)<<3)
//  W1img [t][row 128][168 slots]: jj<160 -> k=jj (pad 8), 336-B rows (bank-free stride)
//  W2T   [t][n 96][k 128] row-major (per-lane global reads)
//  W3B   [t][k 96]
__global__ void k_wcvt(const float* __restrict__ W0, const float* __restrict__ W1,
                       const float* __restrict__ W2, const float* __restrict__ W3,
                       u16* __restrict__ W0img, u16* __restrict__ W1img,
                       u16* __restrict__ W2T, u16* __restrict__ W3B) {
  int id = blockIdx.x * 256 + threadIdx.x;
  if (id < 245760) {
    int t = id / 61440, r1 = id % 61440;
    int kc = r1 / 10240, r2 = r1 % 10240;
    int r = r2 / 64, jj = r2 % 64;
    int klb = (jj * 2) ^ ((r & 7) << 4) ^ ((r & 8) << 3);
    int k = kc * 64 + (klb >> 1);
    W0img[id] = f2b(W0[t * 61440 + k * 160 + r]);
  } else if ((id -= 245760) < 86016) {
    int t = id / 21504, r1 = id % 21504;
    int r = r1 / 168, jj = r1 % 168;
    W1img[id] = (jj < 160) ? f2b(W1[t * 20480 + jj * 128 + r]) : (u16)0;
  } else if ((id -= 86016) < 49152) {
    int t = id / 12288, r1 = id % 12288;
    int n = r1 / 128, k = r1 % 128;
    W2T[id] = f2b(W2[t * 12288 + k * 96 + n]);
  } else if ((id -= 49152) < 384) {
    int t = id / 96, k = id % 96;
    W3B[id] = f2b(W3[t * 96 + k]);
  }
}

// ---------------- fused MFMA MLP ----------------
// LDS carve, total 81920 B exactly -> 2 blocks/CU:
//   stgA [0,32768):      2 x fp32 A-chunk [64 atoms][256 B], swizzle (r&15)<<4 baked via source
//   stgB [32768,73728):  2 x bf16 B-chunk [160 n][128 B], swizzle baked in W0img
//   after L0: sH0 u16[64][168] @0; w1l 43008 B @21504 (DMA'd W1 image, 336-B rows);
//   after L1: sH1 u16[64][136] @64512;  after L2: sH2 u16[64][104] @0
// L0: A+B staged 2-deep via global_load_lds, vmcnt(9) per phase (9 instr/wave/chunk).
// Zero global loads inside the L0 loop.

__global__ __launch_bounds__(256, 2) void k_mlp(
    const float* __restrict__ aev, const int* __restrict__ sorted,
    const int* __restrict__ counts,
    const u16* __restrict__ W0img, const u16* __restrict__ W1img,
    const u16* __restrict__ W2T, const u16* __restrict__ W3B,
    const float* __restrict__ b0, const float* __restrict__ b1,
    const float* __restrict__ b2, const float* __restrict__ b3,
    float* __restrict__ atom_out)
{
  int type = blockIdx.x, tile = blockIdx.y;
  int c0 = counts[0], c1 = counts[1], c2 = counts[2], c3 = counts[3];
  int cnt = (type == 0) ? c0 : (type == 1) ? c1 : (type == 2) ? c2 : c3;
  if (tile * 64 >= cnt) return;
  int off = 0;
  if (type > 0) off += c0;
  if (type > 1) off += c1;
  if (type > 2) off += c2;

  __shared__ uint4 smem4[5120];          // 81920 B
  u8* smem = (u8*)smem4;
  u8*  stgA = smem;                      // [2][16384]
  u8*  stgB = smem + 32768;              // [2][20480]
  u16* sH0  = (u16*)smem;                // [64][168]
  u8*  w1l  = smem + 21504;              // 43008 B
  u16* sH1  = (u16*)(smem + 64512);      // [64][136]
  u16* sH2  = (u16*)smem;                // [64][104]

  int tid = threadIdx.x, lane = tid & 63, w = tid >> 6;
  int wm = w & 1, wn = w >> 1, l15 = lane & 15, lk = lane >> 4;
  int base = off + tile * 64, nvalid = min(64, cnt - tile * 64);

  // A staging sources: lane covers row rr = w*16 + i*4 + (lane>>4), 16-B col (lane&15)*16,
  // fetching the global piece that belongs at its LINEAR lds slot (inverse swizzle).
  int r4 = lane >> 4, c16 = (lane & 15) << 4;
  const float *gA0, *gA1, *gA2, *gA3;
  {
    int r0 = w*16 + 0 + r4, r1 = w*16 + 4 + r4, r2 = w*16 + 8 + r4, r3 = w*16 + 12 + r4;
    gA0 = aev + (size_t)sorted[base + min(r0, nvalid-1)] * DD + ((c16 ^ ((r0 & 15) << 4)) >> 2);
    gA1 = aev + (size_t)sorted[base + min(r1, nvalid-1)] * DD + ((c16 ^ ((r1 & 15) << 4)) >> 2);
    gA2 = aev + (size_t)sorted[base + min(r2, nvalid-1)] * DD + ((c16 ^ ((r2 & 15) << 4)) >> 2);
    gA3 = aev + (size_t)sorted[base + min(r3, nvalid-1)] * DD + ((c16 ^ ((r3 & 15) << 4)) >> 2);
  }
  // B staging source: image is the exact LDS byte layout -> linear coalesced copy
  const u8* gB = (const u8*)W0img + (size_t)type * 122880 + w * 5120 + lane * 16;
  u8* dA = stgA + w * 4096;   // wave-uniform dests (lane*16 added by HW)
  u8* dB = stgB + w * 5120;

#define STAGE(kc, b) do { \
    gl_lds16(gA0 + (kc) * 64, dA + (b) * 16384 + 0);    \
    gl_lds16(gA1 + (kc) * 64, dA + (b) * 16384 + 1024); \
    gl_lds16(gA2 + (kc) * 64, dA + (b) * 16384 + 2048); \
    gl_lds16(gA3 + (kc) * 64, dA + (b) * 16384 + 3072); \
    gl_lds16(gB + (kc) * 20480 + 0,    dB + (b) * 20480 + 0);    \
    gl_lds16(gB + (kc) * 20480 + 1024, dB + (b) * 20480 + 1024); \
    gl_lds16(gB + (kc) * 20480 + 2048, dB + (b) * 20480 + 2048); \
    gl_lds16(gB + (kc) * 20480 + 3072, dB + (b) * 20480 + 3072); \
    gl_lds16(gB + (kc) * 20480 + 4096, dB + (b) * 20480 + 4096); \
  } while (0)

  // fragment read bases
  int swA = l15 << 4;                                   // (rowA&15)<<4, rowA&15 == l15
  int swB = ((l15 & 7) << 4) ^ ((l15 & 8) << 3);        // matches W0img bake
  int rA0 = (wm * 32 + l15) * 256, rA1 = rA0 + 4096;    // byte offsets
  int rB  = (wn * 80 + l15) * 128;

  f32x4 acc0[2][5];
  #pragma unroll
  for (int mt = 0; mt < 2; ++mt)
    #pragma unroll
    for (int nt = 0; nt < 5; ++nt) acc0[mt][nt] = f32x4{0.f, 0.f, 0.f, 0.f};

  STAGE(0, 0);
  STAGE(1, 1);

#define PHASE(KC, WN) do { \
    asm volatile("s_waitcnt vmcnt(" #WN ")" ::: "memory"); \
    __builtin_amdgcn_sched_barrier(0); \
    __builtin_amdgcn_s_barrier(); \
    __builtin_amdgcn_sched_barrier(0); \
    const u8* aB = stgA + ((KC) & 1) * 16384; \
    const u8* bB = stgB + ((KC) & 1) * 20480; \
    _Pragma("unroll") \
    for (int ks = 0; ks < 2; ++ks) { \
      int kb = ks * 128 + lk * 32; \
      bhalf8 af[2], bf[5]; \
      af[0] = pack8(*(const float4*)(aB + rA0 + ((kb)      ^ swA)), \
                    *(const float4*)(aB + rA0 + ((kb + 16) ^ swA))); \
      af[1] = pack8(*(const float4*)(aB + rA1 + ((kb)      ^ swA)), \
                    *(const float4*)(aB + rA1 + ((kb + 16) ^ swA))); \
      int bc = (ks * 64 + lk * 16) ^ swB; \
      _Pragma("unroll") \
      for (int nt = 0; nt < 5; ++nt) \
        bf[nt] = *(const bhalf8*)(bB + rB + nt * 2048 + bc); \
      _Pragma("unroll") \
      for (int mt = 0; mt < 2; ++mt) \
        _Pragma("unroll") \
        for (int nt = 0; nt < 5; ++nt) \
          acc0[mt][nt] = __builtin_amdgcn_mfma_f32_16x16x32_bf16(af[mt], bf[nt], acc0[mt][nt], 0, 0, 0); \
    } \
    asm volatile("s_waitcnt lgkmcnt(0)" ::: "memory"); \
    __builtin_amdgcn_sched_barrier(0); \
    __builtin_amdgcn_s_barrier(); \
    if ((KC) < 4) STAGE((KC) + 2, (KC) & 1); \
  } while (0)

  PHASE(0, 9); PHASE(1, 9); PHASE(2, 9); PHASE(3, 9); PHASE(4, 9); PHASE(5, 0);
#undef PHASE
#undef STAGE

  // stage W1 image (42 KB) into freed staging space; hidden under L0 epilogue
  {
    const u8* gW1 = (const u8*)W1img + (size_t)type * 43008 + lane * 16;
    #pragma unroll
    for (int i = 0; i < 11; ++i) {
      int j = w + 4 * i;                 // wave-uniform
      if (j < 42) gl_lds16(gW1 + j * 1024, w1l + j * 1024);
    }
  }

  // epilogue L0 -> sH0 (overlays stgA; all readers retired at last phase barrier)
  #pragma unroll
  for (int mt = 0; mt < 2; ++mt)
    #pragma unroll
    for (int nt = 0; nt < 5; ++nt) {
      int col = wn * 80 + nt * 16 + l15;
      float bias = b0[type * 160 + col];
      #pragma unroll
      for (int i = 0; i < 4; ++i) {
        int row = wm * 32 + mt * 16 + lk * 4 + i;
        sH0[row * 168 + col] = f2b(celu_f(acc0[mt][nt][i] + bias));
      }
    }
  asm volatile("s_waitcnt vmcnt(0) lgkmcnt(0)" ::: "memory");
  __builtin_amdgcn_sched_barrier(0);
  __builtin_amdgcn_s_barrier();
  __builtin_amdgcn_sched_barrier(0);

  // ---------- Layer 1: [64 x 160] @ [160 x 128], A from sH0, B from w1l ----------
  f32x4 acc1[2][4];
  #pragma unroll
  for (int mt = 0; mt < 2; ++mt)
    #pragma unroll
    for (int nt = 0; nt < 4; ++nt) acc1[mt][nt] = f32x4{0.f, 0.f, 0.f, 0.f};

  #pragma unroll
  for (int kc = 0; kc < 5; ++kc) {
    bhalf8 af[2], bf[4];
    #pragma unroll
    for (int mt = 0; mt < 2; ++mt)
      af[mt] = *(const bhalf8*)&sH0[(wm*32 + mt*16 + l15) * 168 + kc * 32 + lk * 8];
    #pragma unroll
    for (int nt = 0; nt < 4; ++nt)
      bf[nt] = *(const bhalf8*)(w1l + (wn*64 + nt*16 + l15) * 336 + kc * 64 + lk * 16);
    #pragma unroll
    for (int mt = 0; mt < 2; ++mt)
      #pragma unroll
      for (int nt = 0; nt < 4; ++nt)
        acc1[mt][nt] = __builtin_amdgcn_mfma_f32_16x16x32_bf16(af[mt], bf[nt], acc1[mt][nt], 0, 0, 0);
  }
  // epilogue L1 -> sH1 (region disjoint from sH0/w1l)
  #pragma unroll
  for (int mt = 0; mt < 2; ++mt)
    #pragma unroll
    for (int nt = 0; nt < 4; ++nt) {
      int col = wn * 64 + nt * 16 + l15;
      float bias = b1[type * 128 + col];
      #pragma unroll
      for (int i = 0; i < 4; ++i) {
        int row = wm * 32 + mt * 16 + lk * 4 + i;
        sH1[row * 136 + col] = f2b(celu_f(acc1[mt][nt][i] + bias));
      }
    }
  __syncthreads();

  // ---------- Layer 2: [64 x 128] @ [128 x 96], B per-lane from L2$ ----------
  const u16* b2p = W2T + type * 12288 + (wn * 48 + l15) * 128 + lk * 8;
  f32x4 acc2[2][3];
  #pragma unroll
  for (int mt = 0; mt < 2; ++mt)
    #pragma unroll
    for (int nt = 0; nt < 3; ++nt) acc2[mt][nt] = f32x4{0.f, 0.f, 0.f, 0.f};

  #pragma unroll
  for (int kc = 0; kc < 4; ++kc) {
    bhalf8 af[2], bf[3];
    #pragma unroll
    for (int mt = 0; mt < 2; ++mt)
      af[mt] = *(const bhalf8*)&sH1[(wm*32 + mt*16 + l15) * 136 + kc * 32 + lk * 8];
    #pragma unroll
    for (int nt = 0; nt < 3; ++nt)
      bf[nt] = *(const bhalf8*)&b2p[nt * 2048 + kc * 32];
    #pragma unroll
    for (int mt = 0; mt < 2; ++mt)
      #pragma unroll
      for (int nt = 0; nt < 3; ++nt)
        acc2[mt][nt] = __builtin_amdgcn_mfma_f32_16x16x32_bf16(af[mt], bf[nt], acc2[mt][nt], 0, 0, 0);
  }
  // epilogue L2 -> sH2 (overlays sH0; readers retired before __syncthreads above)
  #pragma unroll
  for (int mt = 0; mt < 2; ++mt)
    #pragma unroll
    for (int nt = 0; nt < 3; ++nt) {
      int col = wn * 48 + nt * 16 + l15;
      float bias = b2[type * 96 + col];
      #pragma unroll
      for (int i = 0; i < 4; ++i) {
        int row = wm * 32 + mt * 16 + lk * 4 + i;
        sH2[row * 104 + col] = f2b(celu_f(acc2[mt][nt][i] + bias));
      }
    }
  __syncthreads();

  // ---------- Layer 3: [64 x 96] @ [96 x 1] ----------
  {
    int atom = tid >> 2;
    int q = tid & 3;
    const u16* w3 = W3B + type * 96 + q * 24;
    const u16* hrow = sH2 + atom * 104 + q * 24;
    float s = 0.f;
    #pragma unroll
    for (int i = 0; i < 3; ++i) {
      union { bhalf8 v; u16 u[8]; } hu, wu;
      hu.v = *(const bhalf8*)&hrow[i * 8];
      wu.v = *(const bhalf8*)&w3[i * 8];
      #pragma unroll
      for (int j = 0; j < 8; ++j)
        s += b2f(hu.u[j]) * b2f(wu.u[j]);
    }
    s += __shfl_xor(s, 1);
    s += __shfl_xor(s, 2);
    if (q == 0 && atom < nvalid)
      atom_out[sorted[base + atom]] = s + b3[type];
  }
}

__global__ void k_reduce(const float* __restrict__ atom_out, float* __restrict__ out_e) {
  int mol = blockIdx.x;
  int lane = threadIdx.x;
  float v = atom_out[mol * 64 + lane];
  #pragma unroll
  for (int m = 32; m >= 1; m >>= 1) v += __shfl_xor(v, m);
  if (lane == 0) out_e[mol] = v;
}

// ---------------- launch ----------------

extern "C" void kernel_launch(void* const* d_in, const int* in_sizes, int n_in,
                              void* d_out, int out_size, void* d_ws, size_t ws_size,
                              hipStream_t stream) {
  const int*   species = (const int*)d_in[0];
  const float* aev = (const float*)d_in[1];
  const float* W0 = (const float*)d_in[2];
  const float* b0 = (const float*)d_in[3];
  const float* W1 = (const float*)d_in[4];
  const float* b1 = (const float*)d_in[5];
  const float* W2 = (const float*)d_in[6];
  const float* b2 = (const float*)d_in[7];
  const float* W3 = (const float*)d_in[8];
  const float* b3 = (const float*)d_in[9];
  float* out = (float*)d_out;

  unsigned char* ws = (unsigned char*)d_ws;
  int* counts = (int*)(ws + 0);                 // [4] counts + pad + [4] cursors
  int* sorted = (int*)(ws + 64);                // int[NN]
  float* atom_out = (float*)(ws + 524352);      // float[NN]
  u16* W0img = (u16*)(ws + 1048640);            // 245760 elems
  u16* W1img = (u16*)(ws + 1540160);            // 86016 elems
  u16* W2T   = (u16*)(ws + 1712192);            // 49152 elems
  u16* W3B   = (u16*)(ws + 1810496);            // 384 elems

  hipMemsetAsync(counts, 0, 48, stream);
  k_count<<<NN / 256, 256, 0, stream>>>(species, counts, out);
  k_scatter<<<NN / 256, 256, 0, stream>>>(species, counts, counts + 8, sorted);
  k_wcvt<<<1490, 256, 0, stream>>>(W0, W1, W2, W3, W0img, W1img, W2T, W3B);
  k_mlp<<<dim3(4, 2048), 256, 0, stream>>>(aev, sorted, counts,
        W0img, W1img, W2T, W3B, b0, b1, b2, b3, atom_out);
  k_reduce<<<NB, 64, 0, stream>>>(atom_out, out + NN);
}

// Round 6
// 84.314 us; speedup vs baseline: 1.8192x; 1.2054x over previous
//
#include <hip/hip_runtime.h>
#include <hip/hip_bf16.h>

#define DD 384
#define NB 2048
#define NA 64
#define NN (NB*NA)

using bhalf8 = __attribute__((ext_vector_type(8))) __bf16;
using f32x4  = __attribute__((ext_vector_type(4))) float;
typedef unsigned short u16;
typedef unsigned char u8;

#define AS1 __attribute__((address_space(1)))
#define AS3 __attribute__((address_space(3)))

__device__ __forceinline__ void gl_lds16(const void* g, void* l) {
  __builtin_amdgcn_global_load_lds((const AS1 void*)g, (AS3 void*)l, 16, 0, 0);
}

__device__ __forceinline__ u16 f2b(float f) {
  __hip_bfloat16 h = __float2bfloat16(f);
  union { __hip_bfloat16 h; u16 u; } c; c.h = h; return c.u;
}
__device__ __forceinline__ float b2f(u16 u) {
  union { unsigned int i; float f; } c; c.i = ((unsigned int)u) << 16; return c.f;
}
__device__ __forceinline__ float celu_f(float v) {
  return v > 0.f ? v : 0.1f * (__expf(v * 10.f) - 1.f);
}
__device__ __forceinline__ bhalf8 pack8(float4 a, float4 b) {
  union { u16 us[8]; bhalf8 v; } t;
  t.us[0]=f2b(a.x); t.us[1]=f2b(a.y); t.us[2]=f2b(a.z); t.us[3]=f2b(a.w);
  t.us[4]=f2b(b.x); t.us[5]=f2b(b.y); t.us[6]=f2b(b.z); t.us[7]=f2b(b.w);
  return t.v;
}

// ---------------- prep: count + build weight images (fused) ----------------
// B-image layout (shared by W0/W1/W2): per chunk kc (K=32): [R rows][4 slots][8 bf16],
// slot s holds k-slot j = s ^ ((r>>1)&3)  (bank-optimal for b128 frag reads).
// W0img: [t][12 kc][176 r] (rows 160..175 zero-pad; 11264 B/chunk)
// W1img: [t][ 5 kc][128 r] (8192 B/chunk)
// W2img: [t][ 4 kc][128 r] (rows 96..127 zero-pad; 8192 B/chunk)

__global__ void k_prep(const int* __restrict__ species, int* __restrict__ counts,
                       float* __restrict__ out_sp,
                       const float* __restrict__ W0, const float* __restrict__ W1,
                       const float* __restrict__ W2, const float* __restrict__ W3,
                       u16* __restrict__ W0img, u16* __restrict__ W1img,
                       u16* __restrict__ W2img, u16* __restrict__ W3B) {
  int tid = threadIdx.x;
  int id = blockIdx.x * 256 + tid;
  // ---- species count (blocks 0..511 cover all NN atoms) ----
  if (blockIdx.x < 512) {
    __shared__ int lcnt[4];
    if (tid < 4) lcnt[tid] = 0;
    __syncthreads();
    int s = species[id];
    out_sp[id] = (float)s;
    atomicAdd(&lcnt[s], 1);
    __syncthreads();
    if (tid < 4) atomicAdd(&counts[tid], lcnt[tid]);
  }
  // ---- weight image build ----
  if (id < 270336) {
    int t = id / 67584, r1 = id % 67584;
    int kc = r1 / 5632, r2 = r1 % 5632;
    int r = r2 >> 5, rem = r2 & 31, s = rem >> 3, e = rem & 7;
    u16 v = 0;
    if (r < 160) {
      int k = kc * 32 + (s ^ ((r >> 1) & 3)) * 8 + e;
      v = f2b(W0[t * 61440 + k * 160 + r]);
    }
    W0img[id] = v;
  } else if ((id -= 270336) < 81920) {
    int t = id / 20480, r1 = id % 20480;
    int kc = r1 / 4096, r2 = r1 % 4096;
    int r = r2 >> 5, rem = r2 & 31, s = rem >> 3, e = rem & 7;
    int k = kc * 32 + (s ^ ((r >> 1) & 3)) * 8 + e;
    W1img[id] = f2b(W1[t * 20480 + k * 128 + r]);
  } else if ((id -= 81920) < 65536) {
    int t = id / 16384, r1 = id % 16384;
    int kc = r1 / 4096, r2 = r1 % 4096;
    int r = r2 >> 5, rem = r2 & 31, s = rem >> 3, e = rem & 7;
    u16 v = 0;
    if (r < 96) {
      int k = kc * 32 + (s ^ ((r >> 1) & 3)) * 8 + e;
      v = f2b(W2[t * 12288 + k * 96 + r]);
    }
    W2img[id] = v;
  } else if ((id -= 65536) < 384) {
    W3B[id] = f2b(W3[id]);
  }
}

__global__ void k_scatter(const int* __restrict__ species, const int* __restrict__ counts,
                          int* __restrict__ cursors, int* __restrict__ sorted) {
  __shared__ int lcnt[4];
  __shared__ int lbase[4];
  int tid = threadIdx.x;
  if (tid < 4) lcnt[tid] = 0;
  __syncthreads();
  int i = blockIdx.x * 256 + tid;
  int s = species[i];
  int lpos = atomicAdd(&lcnt[s], 1);
  __syncthreads();
  if (tid < 4) {
    int offs = 0;
    #pragma unroll
    for (int t = 0; t < 4; ++t) if (t < tid) offs += counts[t];
    lbase[tid] = offs + atomicAdd(&cursors[tid], lcnt[tid]);
  }
  __syncthreads();
  sorted[lbase[s] + lpos] = i;
}

// ---------------- fused MFMA MLP: 21-phase uniform pipeline ----------------
// LDS carve, 44032 B total -> 3 blocks/CU (12 waves/CU):
//   Bst [0,22528):      2 x 11264-B B-chunk buffers (W0 / W1 / W2 stream through)
//   Ast [22528,38912):  2 x 8192-B A-chunk buffers (fp32, swizzled slots; L0 only)
//   sH0 [22528,44032):  u16[64][168]  (overlays Ast after L0)
//   sH1 [22528,39936):  u16[64][136]  (overlays sH0 after L1; barrier-protected)
//   sH2 [22528,35840):  u16[64][104]
// Chunks (K=32): 12 W0 + 5 W1 + 4 W2 = 21, buf = g&1, staged 2-ahead; counted
// vmcnt never drains mid-pipeline; layer epilogues use lgkmcnt(0)-only barriers.
// A-chunk [64 r][8 slots x 16B], slot s holds k-slot s^(r&7) (source-baked).

__global__ __launch_bounds__(256, 3) void k_mlp(
    const float* __restrict__ aev, const int* __restrict__ sorted,
    const int* __restrict__ counts,
    const u16* __restrict__ W0img, const u16* __restrict__ W1img,
    const u16* __restrict__ W2img, const u16* __restrict__ W3B,
    const float* __restrict__ b0, const float* __restrict__ b1,
    const float* __restrict__ b2, const float* __restrict__ b3,
    float* __restrict__ atom_out)
{
  int type = blockIdx.x, tile = blockIdx.y;
  int c0 = counts[0], c1 = counts[1], c2 = counts[2], c3 = counts[3];
  int cnt = (type == 0) ? c0 : (type == 1) ? c1 : (type == 2) ? c2 : c3;
  if (tile * 64 >= cnt) return;
  int off = 0;
  if (type > 0) off += c0;
  if (type > 1) off += c1;
  if (type > 2) off += c2;

  __shared__ uint4 smem4[2752];            // 44032 B
  u8* smem = (u8*)smem4;
  u8*  Bst = smem;                         // [2][11264]
  u8*  Ast = smem + 22528;                 // [2][8192]
  u16* sH0 = (u16*)(smem + 22528);         // [64][168]
  u16* sH1 = (u16*)(smem + 22528);         // [64][136]
  u16* sH2 = (u16*)(smem + 22528);         // [64][104]

  int tid = threadIdx.x, lane = tid & 63, w = tid >> 6;
  int wm = w & 1, wn = w >> 1, l15 = lane & 15, lk = lane >> 4;
  int base = off + tile * 64, nvalid = min(64, cnt - tile * 64);

  // ---- bias preload (before any staging: keeps vmcnt counting exact) ----
  float bia0[5], bia1[4], bia2[3], bia3;
  #pragma unroll
  for (int nt = 0; nt < 5; ++nt) bia0[nt] = b0[type * 160 + wn * 80 + nt * 16 + l15];
  #pragma unroll
  for (int nt = 0; nt < 4; ++nt) bia1[nt] = b1[type * 128 + wn * 64 + nt * 16 + l15];
  #pragma unroll
  for (int nt = 0; nt < 3; ++nt) bia2[nt] = b2[type * 96 + wn * 48 + nt * 16 + l15];
  bia3 = b3[type];

  // ---- staging source pointers ----
  // A: wave w stages segs 2w,2w+1 (rows w*16..w*16+16); lane l -> row seg*8+(l>>3),
  //    slot l&7; global fetch = k-slot (l&7)^(row&7) (inverse swizzle).
  int arow0 = w * 16 + (lane >> 3), arow1 = arow0 + 8;
  const float* a0 = aev + (size_t)sorted[base + min(arow0, nvalid - 1)] * DD
                    + (((lane & 7) ^ (arow0 & 7)) << 2);
  const float* a1 = aev + (size_t)sorted[base + min(arow1, nvalid - 1)] * DD
                    + (((lane & 7) ^ (arow1 & 7)) << 2);
  // B: linear image copies; wave w covers segs {w, w+4, (w+8 if w<3)} (L0) / {w, w+4} (W1/W2)
  const u8* gB0 = (const u8*)W0img + (size_t)type * 135168 + w * 1024 + lane * 16;
  const u8* gW1 = (const u8*)W1img + (size_t)type * 40960  + w * 1024 + lane * 16;
  const u8* gW2 = (const u8*)W2img + (size_t)type * 32768  + w * 1024 + lane * 16;
  u8* dA = Ast + 2 * w * 1024;             // wave-uniform dests
  u8* dB = Bst + w * 1024;

#define STG_L0(KC, B_) do { \
    gl_lds16(a0 + (KC) * 32, dA + (B_) * 8192); \
    gl_lds16(a1 + (KC) * 32, dA + (B_) * 8192 + 1024); \
    gl_lds16(gB0 + (KC) * 11264,        dB + (B_) * 11264); \
    gl_lds16(gB0 + (KC) * 11264 + 4096, dB + (B_) * 11264 + 4096); \
    if (w < 3) gl_lds16(gB0 + (KC) * 11264 + 8192, dB + (B_) * 11264 + 8192); \
  } while (0)
#define STG_W(IMG, KC, B_) do { \
    gl_lds16((IMG) + (KC) * 8192,        dB + (B_) * 11264); \
    gl_lds16((IMG) + (KC) * 8192 + 4096, dB + (B_) * 11264 + 4096); \
  } while (0)

  // ---- per-thread fragment offsets ----
  int rA0 = wm * 32 + l15, rA1 = rA0 + 16;
  int sAa = (((2 * lk)     ^ (rA0 & 7)) << 4);   // rA1&7 == rA0&7
  int sAb = (((2 * lk + 1) ^ (rA0 & 7)) << 4);
  int aoff0 = rA0 * 128, aoff1 = rA1 * 128;
  int bsw = (lk ^ ((l15 >> 1) & 3)) << 4;        // (r>>1)&3 == (l15>>1)&3 for all frag rows

#define TOPW(WN) \
  asm volatile("s_waitcnt vmcnt(" #WN ")" ::: "memory"); \
  __builtin_amdgcn_sched_barrier(0); \
  __builtin_amdgcn_s_barrier(); \
  __builtin_amdgcn_sched_barrier(0);
#define TAILW() \
  asm volatile("s_waitcnt lgkmcnt(0)" ::: "memory"); \
  __builtin_amdgcn_sched_barrier(0); \
  __builtin_amdgcn_s_barrier(); \
  __builtin_amdgcn_sched_barrier(0);

  // ---------- Layer 0: 12 phases ----------
  f32x4 acc0[2][5];
  #pragma unroll
  for (int mt = 0; mt < 2; ++mt)
    #pragma unroll
    for (int nt = 0; nt < 5; ++nt) acc0[mt][nt] = f32x4{0.f, 0.f, 0.f, 0.f};

  STG_L0(0, 0);
  STG_L0(1, 1);

#define PHA(KC, WN, STG_) \
  TOPW(WN) \
  { const u8* bA = Ast + ((KC) & 1) * 8192; \
    const u8* bB = Bst + ((KC) & 1) * 11264; \
    bhalf8 af0 = pack8(*(const float4*)(bA + aoff0 + sAa), *(const float4*)(bA + aoff0 + sAb)); \
    bhalf8 af1 = pack8(*(const float4*)(bA + aoff1 + sAa), *(const float4*)(bA + aoff1 + sAb)); \
    bhalf8 bf[5]; \
    _Pragma("unroll") \
    for (int nt = 0; nt < 5; ++nt) \
      bf[nt] = *(const bhalf8*)(bB + ((wn * 80 + nt * 16 + l15) << 6) + bsw); \
    _Pragma("unroll") \
    for (int nt = 0; nt < 5; ++nt) { \
      acc0[0][nt] = __builtin_amdgcn_mfma_f32_16x16x32_bf16(af0, bf[nt], acc0[0][nt], 0, 0, 0); \
      acc0[1][nt] = __builtin_amdgcn_mfma_f32_16x16x32_bf16(af1, bf[nt], acc0[1][nt], 0, 0, 0); \
    } } \
  TAILW() \
  STG_;

  PHA(0, 4, STG_L0(2, 0))  PHA(1, 4, STG_L0(3, 1))  PHA(2, 4, STG_L0(4, 0))
  PHA(3, 4, STG_L0(5, 1))  PHA(4, 4, STG_L0(6, 0))  PHA(5, 4, STG_L0(7, 1))
  PHA(6, 4, STG_L0(8, 0))  PHA(7, 4, STG_L0(9, 1))  PHA(8, 4, STG_L0(10, 0))
  PHA(9, 4, STG_L0(11, 1)) PHA(10, 4, STG_W(gW1, 0, 0)) PHA(11, 2, STG_W(gW1, 1, 1))
#undef PHA

  // L0 epilogue -> sH0 (overlays Ast, dead; lgkm-only barrier keeps W1 DMA in flight)
  #pragma unroll
  for (int mt = 0; mt < 2; ++mt)
    #pragma unroll
    for (int nt = 0; nt < 5; ++nt) {
      int col = wn * 80 + nt * 16 + l15;
      #pragma unroll
      for (int i = 0; i < 4; ++i) {
        int row = wm * 32 + mt * 16 + lk * 4 + i;
        sH0[row * 168 + col] = f2b(celu_f(acc0[mt][nt][i] + bia0[nt]));
      }
    }
  asm volatile("s_waitcnt lgkmcnt(0)" ::: "memory");
  __builtin_amdgcn_sched_barrier(0);

  // ---------- Layer 1: 5 phases (chunks 12..16, buf = kc&1) ----------
  f32x4 acc1[2][4];
  #pragma unroll
  for (int mt = 0; mt < 2; ++mt)
    #pragma unroll
    for (int nt = 0; nt < 4; ++nt) acc1[mt][nt] = f32x4{0.f, 0.f, 0.f, 0.f};

#define PHB(KC, WN, STG_) \
  TOPW(WN) \
  { const u8* bB = Bst + ((KC) & 1) * 11264; \
    bhalf8 af0 = *(const bhalf8*)&sH0[(wm * 32 + l15) * 168 + (KC) * 32 + lk * 8]; \
    bhalf8 af1 = *(const bhalf8*)&sH0[(wm * 32 + 16 + l15) * 168 + (KC) * 32 + lk * 8]; \
    bhalf8 bf[4]; \
    _Pragma("unroll") \
    for (int nt = 0; nt < 4; ++nt) \
      bf[nt] = *(const bhalf8*)(bB + ((wn * 64 + nt * 16 + l15) << 6) + bsw); \
    _Pragma("unroll") \
    for (int nt = 0; nt < 4; ++nt) { \
      acc1[0][nt] = __builtin_amdgcn_mfma_f32_16x16x32_bf16(af0, bf[nt], acc1[0][nt], 0, 0, 0); \
      acc1[1][nt] = __builtin_amdgcn_mfma_f32_16x16x32_bf16(af1, bf[nt], acc1[1][nt], 0, 0, 0); \
    } } \
  TAILW() \
  STG_;

  PHB(0, 2, STG_W(gW1, 2, 0)) PHB(1, 2, STG_W(gW1, 3, 1)) PHB(2, 2, STG_W(gW1, 4, 0))
  PHB(3, 2, STG_W(gW2, 0, 1)) PHB(4, 2, STG_W(gW2, 1, 0))
#undef PHB

  // L1 epilogue -> sH1 (overlays sH0; all sH0 reads retired at last TAILW barrier)
  #pragma unroll
  for (int mt = 0; mt < 2; ++mt)
    #pragma unroll
    for (int nt = 0; nt < 4; ++nt) {
      int col = wn * 64 + nt * 16 + l15;
      #pragma unroll
      for (int i = 0; i < 4; ++i) {
        int row = wm * 32 + mt * 16 + lk * 4 + i;
        sH1[row * 136 + col] = f2b(celu_f(acc1[mt][nt][i] + bia1[nt]));
      }
    }
  asm volatile("s_waitcnt lgkmcnt(0)" ::: "memory");
  __builtin_amdgcn_sched_barrier(0);

  // ---------- Layer 2: 4 phases (chunks 17..20, buf = (kc+1)&1) ----------
  f32x4 acc2[2][3];
  #pragma unroll
  for (int mt = 0; mt < 2; ++mt)
    #pragma unroll
    for (int nt = 0; nt < 3; ++nt) acc2[mt][nt] = f32x4{0.f, 0.f, 0.f, 0.f};

#define PHC(KC, WN, STG_) \
  TOPW(WN) \
  { const u8* bB = Bst + (((KC) + 1) & 1) * 11264; \
    bhalf8 af0 = *(const bhalf8*)&sH1[(wm * 32 + l15) * 136 + (KC) * 32 + lk * 8]; \
    bhalf8 af1 = *(const bhalf8*)&sH1[(wm * 32 + 16 + l15) * 136 + (KC) * 32 + lk * 8]; \
    bhalf8 bf[3]; \
    _Pragma("unroll") \
    for (int nt = 0; nt < 3; ++nt) \
      bf[nt] = *(const bhalf8*)(bB + ((wn * 48 + nt * 16 + l15) << 6) + bsw); \
    _Pragma("unroll") \
    for (int nt = 0; nt < 3; ++nt) { \
      acc2[0][nt] = __builtin_amdgcn_mfma_f32_16x16x32_bf16(af0, bf[nt], acc2[0][nt], 0, 0, 0); \
      acc2[1][nt] = __builtin_amdgcn_mfma_f32_16x16x32_bf16(af1, bf[nt], acc2[1][nt], 0, 0, 0); \
    } } \
  TAILW() \
  STG_;

  PHC(0, 2, STG_W(gW2, 2, 1)) PHC(1, 2, STG_W(gW2, 3, 0)) PHC(2, 2, ) PHC(3, 0, )
#undef PHC
#undef STG_L0
#undef STG_W

  // L2 epilogue -> sH2 (overlays sH1; reads retired at last TAILW barrier)
  #pragma unroll
  for (int mt = 0; mt < 2; ++mt)
    #pragma unroll
    for (int nt = 0; nt < 3; ++nt) {
      int col = wn * 48 + nt * 16 + l15;
      #pragma unroll
      for (int i = 0; i < 4; ++i) {
        int row = wm * 32 + mt * 16 + lk * 4 + i;
        sH2[row * 104 + col] = f2b(celu_f(acc2[mt][nt][i] + bia2[nt]));
      }
    }
  asm volatile("s_waitcnt lgkmcnt(0)" ::: "memory");
  __builtin_amdgcn_sched_barrier(0);
  __builtin_amdgcn_s_barrier();
  __builtin_amdgcn_sched_barrier(0);

  // ---------- Layer 3: [64 x 96] @ [96 x 1] ----------
  {
    int atom = tid >> 2;
    int q = tid & 3;
    const u16* w3 = W3B + type * 96 + q * 24;
    const u16* hrow = sH2 + atom * 104 + q * 24;
    float s = 0.f;
    #pragma unroll
    for (int i = 0; i < 3; ++i) {
      union { bhalf8 v; u16 u[8]; } hu, wu;
      hu.v = *(const bhalf8*)&hrow[i * 8];
      wu.v = *(const bhalf8*)&w3[i * 8];
      #pragma unroll
      for (int j = 0; j < 8; ++j)
        s += b2f(hu.u[j]) * b2f(wu.u[j]);
    }
    s += __shfl_xor(s, 1);
    s += __shfl_xor(s, 2);
    if (q == 0 && atom < nvalid)
      atom_out[sorted[base + atom]] = s + bia3;
  }
}

__global__ void k_reduce(const float* __restrict__ atom_out, float* __restrict__ out_e) {
  int mol = blockIdx.x;
  int lane = threadIdx.x;
  float v = atom_out[mol * 64 + lane];
  #pragma unroll
  for (int m = 32; m >= 1; m >>= 1) v += __shfl_xor(v, m);
  if (lane == 0) out_e[mol] = v;
}

// ---------------- launch ----------------

extern "C" void kernel_launch(void* const* d_in, const int* in_sizes, int n_in,
                              void* d_out, int out_size, void* d_ws, size_t ws_size,
                              hipStream_t stream) {
  const int*   species = (const int*)d_in[0];
  const float* aev = (const float*)d_in[1];
  const float* W0 = (const float*)d_in[2];
  const float* b0 = (const float*)d_in[3];
  const float* W1 = (const float*)d_in[4];
  const float* b1 = (const float*)d_in[5];
  const float* W2 = (const float*)d_in[6];
  const float* b2 = (const float*)d_in[7];
  const float* W3 = (const float*)d_in[8];
  const float* b3 = (const float*)d_in[9];
  float* out = (float*)d_out;

  unsigned char* ws = (unsigned char*)d_ws;
  int* counts = (int*)(ws + 0);                 // [4] counts + pad + [4] cursors
  int* sorted = (int*)(ws + 64);                // int[NN]
  float* atom_out = (float*)(ws + 524352);      // float[NN]
  u16* W0img = (u16*)(ws + 1048640);            // 270336 u16
  u16* W1img = (u16*)(ws + 1589312);            // 81920 u16
  u16* W2img = (u16*)(ws + 1753152);            // 65536 u16
  u16* W3B   = (u16*)(ws + 1884224);            // 384 u16

  hipMemsetAsync(counts, 0, 48, stream);
  k_prep<<<1634, 256, 0, stream>>>(species, counts, out,
        W0, W1, W2, W3, W0img, W1img, W2img, W3B);
  k_scatter<<<NN / 256, 256, 0, stream>>>(species, counts, counts + 8, sorted);
  k_mlp<<<dim3(4, 2048), 256, 0, stream>>>(aev, sorted, counts,
        W0img, W1img, W2img, W3B, b0, b1, b2, b3, atom_out);
  k_reduce<<<NB, 64, 0, stream>>>(atom_out, out + NN);
}